// Round 2
// baseline (1310.351 us; speedup 1.0000x reference)
//
#include <hip/hip_runtime.h>

typedef unsigned short u16;
typedef __attribute__((ext_vector_type(8))) short short8;
typedef __attribute__((ext_vector_type(4))) float f32x4;

#define MFMA_BF16 __builtin_amdgcn_mfma_f32_16x16x32_bf16

__device__ __forceinline__ u16 f2bf(float f){
  unsigned int u = __builtin_bit_cast(unsigned int, f);
  u += 0x7fffu + ((u >> 16) & 1u);
  return (u16)(u >> 16);
}

// ---------------- fp32 -> fp32 transpose ----------------
__global__ void k_transpose_f(const float* __restrict__ src, float* __restrict__ dst,
                              int rows, int cols)
{
  __shared__ float tile[32][33];
  int c0 = blockIdx.x * 32, r0 = blockIdx.y * 32;
  int tx = threadIdx.x, ty = threadIdx.y;
#pragma unroll
  for (int i = 0; i < 4; ++i){
    int r = ty + i * 8;
    tile[r][tx] = src[(long)(r0 + r) * cols + c0 + tx];
  }
  __syncthreads();
#pragma unroll
  for (int i = 0; i < 4; ++i){
    int r = ty + i * 8;
    dst[(long)(c0 + r) * rows + r0 + tx] = tile[tx][r];
  }
}

// ---------------- fp32 -> bf16 transpose (batched) ----------------
__global__ void k_transpose_b(const float* __restrict__ src, u16* __restrict__ dst,
                              int rows, int cols, long sb, long db)
{
  __shared__ float tile[32][33];
  src += (long)blockIdx.z * sb; dst += (long)blockIdx.z * db;
  int c0 = blockIdx.x * 32, r0 = blockIdx.y * 32;
  int tx = threadIdx.x, ty = threadIdx.y;
#pragma unroll
  for (int i = 0; i < 4; ++i){
    int r = ty + i * 8;
    tile[r][tx] = src[(long)(r0 + r) * cols + c0 + tx];
  }
  __syncthreads();
#pragma unroll
  for (int i = 0; i < 4; ++i){
    int r = ty + i * 8;
    dst[(long)(c0 + r) * rows + r0 + tx] = f2bf(tile[tx][r]);
  }
}

// ---------------- NT MFMA GEMM: C[M,N] = scale * A[M,K] * B[N,K]^T ----------------
// A,B fp32 in global; converted to bf16 while staging to LDS; fp32 accumulate.
// Cf (fp32) and/or Cb (bf16) outputs; either may be null.
__global__ __launch_bounds__(256)
void k_gemm_nt(const float* __restrict__ A, const float* __restrict__ B,
               float* __restrict__ Cf, u16* __restrict__ Cb,
               int M, int N, int K, int lda, int ldb, int ldc,
               long sA, long sB, long sC, float scale)
{
  A += (long)blockIdx.z * sA; B += (long)blockIdx.z * sB;
  if (Cf) Cf += (long)blockIdx.z * sC;
  if (Cb) Cb += (long)blockIdx.z * sC;
  const int n0 = blockIdx.x * 64, m0 = blockIdx.y * 64;
  const int tid = threadIdx.x;
  const int wave = tid >> 6, lane = tid & 63, quad = lane >> 4, l16 = lane & 15;
  __shared__ u16 As[64 * 40];
  __shared__ u16 Bs[64 * 40];
  f32x4 acc[4];
#pragma unroll
  for (int n = 0; n < 4; ++n) acc[n] = (f32x4){0.f, 0.f, 0.f, 0.f};

  const int lr = tid >> 2;          // 0..63 tile row
  const int lc = (tid & 3) * 8;     // 0/8/16/24
  for (int k0 = 0; k0 < K; k0 += 32){
    {
      const float* pa = &A[(long)(m0 + lr) * lda + k0 + lc];
      float4 a0 = *(const float4*)pa;
      float4 a1 = *(const float4*)(pa + 4);
      short8 pk;
      pk[0]=(short)f2bf(a0.x); pk[1]=(short)f2bf(a0.y); pk[2]=(short)f2bf(a0.z); pk[3]=(short)f2bf(a0.w);
      pk[4]=(short)f2bf(a1.x); pk[5]=(short)f2bf(a1.y); pk[6]=(short)f2bf(a1.z); pk[7]=(short)f2bf(a1.w);
      *(short8*)&As[lr * 40 + lc] = pk;
      const float* pb = &B[(long)(n0 + lr) * ldb + k0 + lc];
      float4 b0 = *(const float4*)pb;
      float4 b1 = *(const float4*)(pb + 4);
      short8 qk;
      qk[0]=(short)f2bf(b0.x); qk[1]=(short)f2bf(b0.y); qk[2]=(short)f2bf(b0.z); qk[3]=(short)f2bf(b0.w);
      qk[4]=(short)f2bf(b1.x); qk[5]=(short)f2bf(b1.y); qk[6]=(short)f2bf(b1.z); qk[7]=(short)f2bf(b1.w);
      *(short8*)&Bs[lr * 40 + lc] = qk;
    }
    __syncthreads();
    short8 a = *(const short8*)&As[(wave * 16 + l16) * 40 + quad * 8];
#pragma unroll
    for (int n = 0; n < 4; ++n){
      short8 b = *(const short8*)&Bs[(n * 16 + l16) * 40 + quad * 8];
      acc[n] = MFMA_BF16(a, b, acc[n], 0, 0, 0);
    }
    __syncthreads();
  }
#pragma unroll
  for (int n = 0; n < 4; ++n)
#pragma unroll
    for (int r = 0; r < 4; ++r){
      int row = m0 + wave * 16 + quad * 4 + r;
      int col = n0 + n * 16 + l16;
      float v = acc[n][r] * scale;
      if (Cf) Cf[(long)row * ldc + col] = v;
      if (Cb) Cb[(long)row * ldc + col] = f2bf(v);
    }
}

// ---------------- fused MLA flash attention ----------------
// grid (32 qtiles, 16 heads, 4 batch), 256 threads (4 waves, 16 q-rows each)
__global__ __launch_bounds__(256)
void k_flash(const u16* __restrict__ xq, const u16* __restrict__ Pt,
             const float* __restrict__ ckv, const u16* __restrict__ ckvT,
             const u16* __restrict__ Vt, float* __restrict__ y)
{
  const int qt = blockIdx.x, h = blockIdx.y, b = blockIdx.z;
  const int tid = threadIdx.x;
  const int wave = tid >> 6, lane = tid & 63, quad = lane >> 4, l16 = lane & 15;

  // kvbuf reused as: xq-tile [64][264] / q_lat [64][264] / ckv tile [64][264] /
  //                  ckvT tile [256][72] / ctx [64][264]
  __shared__ u16 kvbuf[256 * 72];   // 36864 B
  __shared__ u16 pbuf[64 * 72];     //  9216 B   -> 46080 B total => 3 blocks/CU

  // ---- phase 0: stage xq tile (bf16), compute q_lat = xq_tile @ Pt[h]^T, park in LDS
  {
    const u16* src = xq + (long)(b * 2048 + qt * 64) * 256;
#pragma unroll
    for (int i = 0; i < 8; ++i){
      int c = tid + i * 256;
      int r = c >> 5, col = (c & 31) * 8;
      *(int4*)&kvbuf[r * 264 + col] = *(const int4*)&src[r * 256 + col];
    }
  }
  __syncthreads();
  short8 aS[8];
  {
    short8 afr[8];
#pragma unroll
    for (int ks = 0; ks < 8; ++ks)
      afr[ks] = *(const short8*)&kvbuf[(wave * 16 + l16) * 264 + ks * 32 + quad * 8];
    __syncthreads();   // everyone captured xq fragments; kvbuf may be overwritten
    const u16* pth = Pt + (long)h * 256 * 256;
#pragma unroll
    for (int n = 0; n < 16; ++n){
      f32x4 acc = (f32x4){0.f, 0.f, 0.f, 0.f};
#pragma unroll
      for (int ks = 0; ks < 8; ++ks){
        short8 bfr = *(const short8*)&pth[(n * 16 + l16) * 256 + ks * 32 + quad * 8];
        acc = MFMA_BF16(afr[ks], bfr, acc, 0, 0, 0);
      }
#pragma unroll
      for (int r = 0; r < 4; ++r)
        kvbuf[(wave * 16 + quad * 4 + r) * 264 + n * 16 + l16] = f2bf(acc[r]);
    }
    __syncthreads();   // q_lat (C-layout write) complete
#pragma unroll
    for (int ks = 0; ks < 8; ++ks)
      aS[ks] = *(const short8*)&kvbuf[(wave * 16 + l16) * 264 + ks * 32 + quad * 8];
    __syncthreads();   // q_lat A-fragments captured in registers; kvbuf free
  }

  // ---- phase 1: online-softmax KV loop
  float mrow[4], lrow[4];
  f32x4 oacc[16];
#pragma unroll
  for (int r = 0; r < 4; ++r){ mrow[r] = -1e30f; lrow[r] = 0.f; }
#pragma unroll
  for (int n = 0; n < 16; ++n) oacc[n] = (f32x4){0.f, 0.f, 0.f, 0.f};

  const float* ckv_b = ckv  + (long)b * 2048 * 256;
  const u16*  ckvT_b = ckvT + (long)b * 256 * 2048;

  for (int st = 0; st <= qt; ++st){
    // stage c_kv tile [64 s][264] (fp32 -> bf16)
#pragma unroll
    for (int i = 0; i < 8; ++i){
      int c = tid + i * 256;
      int r = c >> 5, col = (c & 31) * 8;
      const float* s = &ckv_b[(st * 64 + r) * 256 + col];
      float4 v0 = *(const float4*)s;
      float4 v1 = *(const float4*)(s + 4);
      short8 pk;
      pk[0]=(short)f2bf(v0.x); pk[1]=(short)f2bf(v0.y); pk[2]=(short)f2bf(v0.z); pk[3]=(short)f2bf(v0.w);
      pk[4]=(short)f2bf(v1.x); pk[5]=(short)f2bf(v1.y); pk[6]=(short)f2bf(v1.z); pk[7]=(short)f2bf(v1.w);
      *(short8*)&kvbuf[r * 264 + col] = pk;
    }
    __syncthreads();

    // S = q_lat @ ckv^T : this wave's 16 rows x 64 cols
    f32x4 sacc[4];
#pragma unroll
    for (int n = 0; n < 4; ++n) sacc[n] = (f32x4){0.f, 0.f, 0.f, 0.f};
#pragma unroll
    for (int n = 0; n < 4; ++n){
#pragma unroll
      for (int ks = 0; ks < 8; ++ks){
        short8 bfr = *(const short8*)&kvbuf[(n * 16 + l16) * 264 + ks * 32 + quad * 8];
        sacc[n] = MFMA_BF16(aS[ks], bfr, sacc[n], 0, 0, 0);
      }
    }
    if (st == qt){   // causal mask on diagonal tile
#pragma unroll
      for (int n = 0; n < 4; ++n){
        int s = st * 64 + n * 16 + l16;
#pragma unroll
        for (int r = 0; r < 4; ++r){
          int t = qt * 64 + wave * 16 + quad * 4 + r;
          if (s > t) sacc[n][r] = -1e30f;
        }
      }
    }

    // online softmax (reg r -> row quad*4+r; cols -> 16 lanes of quad)
    float pmat[4][4];
#pragma unroll
    for (int r = 0; r < 4; ++r){
      float rm = fmaxf(fmaxf(sacc[0][r], sacc[1][r]), fmaxf(sacc[2][r], sacc[3][r]));
#pragma unroll
      for (int off = 8; off >= 1; off >>= 1)
        rm = fmaxf(rm, __shfl_xor(rm, off, 64));
      float mnew = fmaxf(mrow[r], rm);
      float alpha = __expf(mrow[r] - mnew);
      mrow[r] = mnew;
      float rs = 0.f;
#pragma unroll
      for (int n = 0; n < 4; ++n){
        float pe = __expf(sacc[n][r] - mnew);
        pmat[n][r] = pe;
        rs += pe;
      }
#pragma unroll
      for (int off = 8; off >= 1; off >>= 1)
        rs += __shfl_xor(rs, off, 64);
      lrow[r] = lrow[r] * alpha + rs;
#pragma unroll
      for (int n = 0; n < 16; ++n) oacc[n][r] *= alpha;
    }
#pragma unroll
    for (int n = 0; n < 4; ++n)
#pragma unroll
      for (int r = 0; r < 4; ++r)
        pbuf[(wave * 16 + quad * 4 + r) * 72 + n * 16 + l16] = f2bf(pmat[n][r]);
    __syncthreads();   // P ready; kvbuf (ckv tile) consumed

    // stage c_kvT tile [256 l][72] (bf16)
#pragma unroll
    for (int i = 0; i < 8; ++i){
      int c = tid + i * 256;
      int r = c >> 3, col = (c & 7) * 8;
      *(int4*)&kvbuf[r * 72 + col] = *(const int4*)&ckvT_b[(long)r * 2048 + st * 64 + col];
    }
    __syncthreads();

    // O += P @ ckv   (16 rows x 256 latent per wave)
    {
      short8 a0 = *(const short8*)&pbuf[(wave * 16 + l16) * 72 + quad * 8];
      short8 a1 = *(const short8*)&pbuf[(wave * 16 + l16) * 72 + 32 + quad * 8];
#pragma unroll
      for (int n = 0; n < 16; ++n){
        short8 b0 = *(const short8*)&kvbuf[(n * 16 + l16) * 72 + quad * 8];
        short8 b1 = *(const short8*)&kvbuf[(n * 16 + l16) * 72 + 32 + quad * 8];
        oacc[n] = MFMA_BF16(a0, b0, oacc[n], 0, 0, 0);
        oacc[n] = MFMA_BF16(a1, b1, oacc[n], 0, 0, 0);
      }
    }
    __syncthreads();   // kvbuf/pbuf consumed before next iteration restage
  }

  // ---- finalize: ctx = O / l, park in LDS (bf16), y = ctx @ v_eff[h]
#pragma unroll
  for (int r = 0; r < 4; ++r){
    float inv = 1.f / lrow[r];
#pragma unroll
    for (int n = 0; n < 16; ++n) oacc[n][r] *= inv;
  }
#pragma unroll
  for (int n = 0; n < 16; ++n)
#pragma unroll
    for (int r = 0; r < 4; ++r)
      kvbuf[(wave * 16 + quad * 4 + r) * 264 + n * 16 + l16] = f2bf(oacc[n][r]);
  __syncthreads();

  {
    const u16* vth = Vt + (long)h * 64 * 256;   // Vt[(h*64+d)*256 + l]
    short8 afr[8];
#pragma unroll
    for (int ks = 0; ks < 8; ++ks)
      afr[ks] = *(const short8*)&kvbuf[(wave * 16 + l16) * 264 + ks * 32 + quad * 8];
#pragma unroll
    for (int n = 0; n < 4; ++n){
      f32x4 acc = (f32x4){0.f, 0.f, 0.f, 0.f};
#pragma unroll
      for (int ks = 0; ks < 8; ++ks){
        short8 bfr = *(const short8*)&vth[(n * 16 + l16) * 256 + ks * 32 + quad * 8];
        acc = MFMA_BF16(afr[ks], bfr, acc, 0, 0, 0);
      }
#pragma unroll
      for (int r = 0; r < 4; ++r){
        int t = qt * 64 + wave * 16 + quad * 4 + r;
        y[((long)b * 2048 + t) * 1024 + h * 64 + n * 16 + l16] = acc[r];
      }
    }
  }
}

extern "C" void kernel_launch(void* const* d_in, const int* in_sizes, int n_in,
                              void* d_out, int out_size, void* d_ws, size_t ws_size,
                              hipStream_t stream)
{
  (void)in_sizes; (void)n_in; (void)out_size; (void)ws_size;
  const float* x    = (const float*)d_in[0];   // (4,2048,1024)
  const float* Wdq  = (const float*)d_in[1];   // (256,1024)
  const float* Wuq  = (const float*)d_in[2];   // (1024,256)
  const float* Wdkv = (const float*)d_in[3];   // (256,1024)
  const float* Wuk  = (const float*)d_in[4];   // (1024,256)
  const float* Wuv  = (const float*)d_in[5];   // (1024,256)
  const float* Wo   = (const float*)d_in[6];   // (1024,1024)

  float* y_out   = (float*)d_out;                      // (4,2048,1024)
  float* ckv_out = y_out + (size_t)4 * 2048 * 1024;    // (4,2048,256) fp32

  // ws layout (bytes), liveness-aliased; total 11.75 MB
  char* base = (char*)d_ws;
  float* wdqT  = (float*)(base + 0);          // 1 MB  (1024,256)   dead after keffT
  float* wuqT  = (float*)(base + 1048576);    // 1 MB  (256,1024)   dead after pt
  float* wukT  = (float*)(base + 2097152);    // 1 MB  (256,1024)   dead after t1T
  float* wuvT  = (float*)(base + 3145728);    // 1 MB  (256,1024)   dead after vt
  u16*   ckvT  = (u16*)  (base + 0);          // 4 MB  (4,256,2048) written after all above dead
  float* t1T   = (float*)(base + 4194304);    // 256 KB (256,256)
  float* keffT = (float*)(base + 4456448);    // 1 MB  (256,1024)
  u16*   pt    = (u16*)  (base + 5505024);    // 2 MB  (16,256,256) scale 1/8 folded
  u16*   vt    = (u16*)  (base + 7602176);    // 512 KB (1024,256)
  u16*   xq    = (u16*)  (base + 8126464);    // 4 MB  (8192,256)

  dim3 tb(32, 8);
  k_transpose_f<<<dim3(32, 8, 1), tb, 0, stream>>>(Wdq, wdqT, 256, 1024);
  k_transpose_f<<<dim3(8, 32, 1), tb, 0, stream>>>(Wuq, wuqT, 1024, 256);
  k_transpose_f<<<dim3(8, 32, 1), tb, 0, stream>>>(Wuk, wukT, 1024, 256);
  k_transpose_f<<<dim3(8, 32, 1), tb, 0, stream>>>(Wuv, wuvT, 1024, 256);

  // T1T[l,a] = sum_c Wuk[c,l] Wuq[c,a]
  k_gemm_nt<<<dim3(4, 4, 1), 256, 0, stream>>>(wukT, wuqT, t1T, (u16*)0,
      256, 256, 1024, 1024, 1024, 256, 0, 0, 0, 1.f);
  // KeffT[l,j] = sum_a T1T[l,a] Wdq[a,j]
  k_gemm_nt<<<dim3(16, 4, 1), 256, 0, stream>>>(t1T, wdqT, keffT, (u16*)0,
      256, 1024, 256, 256, 256, 1024, 0, 0, 0, 1.f);
  // Pt[h][l,a] = (1/8) sum_d KeffT[l,h*64+d] Wuq[h*64+d,a]
  k_gemm_nt<<<dim3(4, 4, 16), 256, 0, stream>>>(keffT, wuqT, (float*)0, pt,
      256, 256, 64, 1024, 1024, 256, 64, 64, 65536, 0.125f);
  // Vt[c,l] = sum_k Wo[c,k] Wuv[k,l]
  k_gemm_nt<<<dim3(4, 16, 1), 256, 0, stream>>>(Wo, wuvT, (float*)0, vt,
      1024, 256, 1024, 1024, 1024, 256, 0, 0, 0, 1.f);
  // xq = x @ Wdq^T (bf16)
  k_gemm_nt<<<dim3(4, 128, 1), 256, 0, stream>>>(x, Wdq, (float*)0, xq,
      8192, 256, 1024, 1024, 1024, 256, 0, 0, 0, 1.f);
  // c_kv = x @ Wdkv^T -> fp32 straight into d_out
  k_gemm_nt<<<dim3(4, 128, 1), 256, 0, stream>>>(x, Wdkv, ckv_out, (u16*)0,
      8192, 256, 1024, 1024, 1024, 256, 0, 0, 0, 1.f);

  // c_kvT (per batch 256 x 2048, bf16)
  k_transpose_b<<<dim3(8, 64, 4), tb, 0, stream>>>(ckv_out, ckvT,
      2048, 256, (long)2048 * 256, (long)256 * 2048);

  k_flash<<<dim3(32, 16, 4), 256, 0, stream>>>(xq, pt, ckv_out, ckvT, vt, y_out);
}

// Round 3
// 1191.526 us; speedup vs baseline: 1.0997x; 1.0997x over previous
//
#include <hip/hip_runtime.h>

typedef unsigned short u16;
typedef __attribute__((ext_vector_type(8))) short short8;
typedef __attribute__((ext_vector_type(4))) float f32x4;

#define MFMA_BF16 __builtin_amdgcn_mfma_f32_16x16x32_bf16

__device__ __forceinline__ u16 f2bf(float f){
  unsigned int u = __builtin_bit_cast(unsigned int, f);
  u += 0x7fffu + ((u >> 16) & 1u);
  return (u16)(u >> 16);
}

// ---------------- fp32 -> fp32 transpose ----------------
__global__ void k_transpose_f(const float* __restrict__ src, float* __restrict__ dst,
                              int rows, int cols)
{
  __shared__ float tile[32][33];
  int c0 = blockIdx.x * 32, r0 = blockIdx.y * 32;
  int tx = threadIdx.x, ty = threadIdx.y;
#pragma unroll
  for (int i = 0; i < 4; ++i){
    int r = ty + i * 8;
    tile[r][tx] = src[(long)(r0 + r) * cols + c0 + tx];
  }
  __syncthreads();
#pragma unroll
  for (int i = 0; i < 4; ++i){
    int r = ty + i * 8;
    dst[(long)(c0 + r) * rows + r0 + tx] = tile[tx][r];
  }
}

// ---------------- fp32 -> bf16 transpose (batched) ----------------
__global__ void k_transpose_b(const float* __restrict__ src, u16* __restrict__ dst,
                              int rows, int cols, long sb, long db)
{
  __shared__ float tile[32][33];
  src += (long)blockIdx.z * sb; dst += (long)blockIdx.z * db;
  int c0 = blockIdx.x * 32, r0 = blockIdx.y * 32;
  int tx = threadIdx.x, ty = threadIdx.y;
#pragma unroll
  for (int i = 0; i < 4; ++i){
    int r = ty + i * 8;
    tile[r][tx] = src[(long)(r0 + r) * cols + c0 + tx];
  }
  __syncthreads();
#pragma unroll
  for (int i = 0; i < 4; ++i){
    int r = ty + i * 8;
    dst[(long)(c0 + r) * rows + r0 + tx] = f2bf(tile[tx][r]);
  }
}

// ---------------- NT MFMA GEMM: C[M,N] = scale * A[M,K] * B[N,K]^T ----------------
__global__ __launch_bounds__(256)
void k_gemm_nt(const float* __restrict__ A, const float* __restrict__ B,
               float* __restrict__ Cf, u16* __restrict__ Cb,
               int M, int N, int K, int lda, int ldb, int ldc,
               long sA, long sB, long sC, float scale)
{
  A += (long)blockIdx.z * sA; B += (long)blockIdx.z * sB;
  if (Cf) Cf += (long)blockIdx.z * sC;
  if (Cb) Cb += (long)blockIdx.z * sC;
  const int n0 = blockIdx.x * 64, m0 = blockIdx.y * 64;
  const int tid = threadIdx.x;
  const int wave = tid >> 6, lane = tid & 63, quad = lane >> 4, l16 = lane & 15;
  __shared__ u16 As[64 * 40];
  __shared__ u16 Bs[64 * 40];
  f32x4 acc[4];
#pragma unroll
  for (int n = 0; n < 4; ++n) acc[n] = (f32x4){0.f, 0.f, 0.f, 0.f};

  const int lr = tid >> 2;
  const int lc = (tid & 3) * 8;
  for (int k0 = 0; k0 < K; k0 += 32){
    {
      const float* pa = &A[(long)(m0 + lr) * lda + k0 + lc];
      float4 a0 = *(const float4*)pa;
      float4 a1 = *(const float4*)(pa + 4);
      short8 pk;
      pk[0]=(short)f2bf(a0.x); pk[1]=(short)f2bf(a0.y); pk[2]=(short)f2bf(a0.z); pk[3]=(short)f2bf(a0.w);
      pk[4]=(short)f2bf(a1.x); pk[5]=(short)f2bf(a1.y); pk[6]=(short)f2bf(a1.z); pk[7]=(short)f2bf(a1.w);
      *(short8*)&As[lr * 40 + lc] = pk;
      const float* pb = &B[(long)(n0 + lr) * ldb + k0 + lc];
      float4 b0 = *(const float4*)pb;
      float4 b1 = *(const float4*)(pb + 4);
      short8 qk;
      qk[0]=(short)f2bf(b0.x); qk[1]=(short)f2bf(b0.y); qk[2]=(short)f2bf(b0.z); qk[3]=(short)f2bf(b0.w);
      qk[4]=(short)f2bf(b1.x); qk[5]=(short)f2bf(b1.y); qk[6]=(short)f2bf(b1.z); qk[7]=(short)f2bf(b1.w);
      *(short8*)&Bs[lr * 40 + lc] = qk;
    }
    __syncthreads();
    short8 a = *(const short8*)&As[(wave * 16 + l16) * 40 + quad * 8];
#pragma unroll
    for (int n = 0; n < 4; ++n){
      short8 b = *(const short8*)&Bs[(n * 16 + l16) * 40 + quad * 8];
      acc[n] = MFMA_BF16(a, b, acc[n], 0, 0, 0);
    }
    __syncthreads();
  }
#pragma unroll
  for (int n = 0; n < 4; ++n)
#pragma unroll
    for (int r = 0; r < 4; ++r){
      int row = m0 + wave * 16 + quad * 4 + r;
      int col = n0 + n * 16 + l16;
      float v = acc[n][r] * scale;
      if (Cf) Cf[(long)row * ldc + col] = v;
      if (Cb) Cb[(long)row * ldc + col] = f2bf(v);
    }
}

// ---------------- fused MLA flash attention (S^T formulation) ----------------
// grid (32 qtiles reversed, 16 heads, 4 batch), 256 threads (4 waves x 16 q-rows)
__global__ __launch_bounds__(256, 2)
void k_flash(const u16* __restrict__ xq, const u16* __restrict__ Pt,
             const u16* __restrict__ ckv_bf, const u16* __restrict__ ckvT,
             const u16* __restrict__ Vt, float* __restrict__ y)
{
  const int qt = 31 - blockIdx.x, h = blockIdx.y, b = blockIdx.z;
  const int tid = threadIdx.x;
  const int wg = tid >> 6, lane = tid & 63, quad = lane >> 4, l16 = lane & 15;

  __shared__ u16 X0[64 * 256];   // ckv tile (swizzled) / q_lat scratch / P / ctx scratch
  __shared__ u16 X1[256 * 64];   // ckvT tile (swizzled)

  const int trow = wg * 16 + l16;              // this wave's t row (0..63) for lane's l16
  const long tglob = (long)b * 2048 + qt * 64;
  const int sw_t = trow & 7;

  // ---- phase 0: q_lat^T = Pt[h](A) x xq(B); park q_lat in X0, read back B-frags aS
  short8 aS[8];
  {
    short8 bq[8];
    const u16* xr = xq + (tglob + trow) * 256;
#pragma unroll
    for (int ks = 0; ks < 8; ++ks)
      bq[ks] = *(const short8*)&xr[ks * 32 + quad * 8];
    const u16* pth = Pt + (long)h * 65536;
#pragma unroll
    for (int mb = 0; mb < 16; ++mb){
      f32x4 acc = (f32x4){0.f, 0.f, 0.f, 0.f};
#pragma unroll
      for (int ks = 0; ks < 8; ++ks){
        short8 pa = *(const short8*)&pth[(mb * 16 + l16) * 256 + ks * 32 + quad * 8];
        acc = MFMA_BF16(pa, bq[ks], acc, 0, 0, 0);
      }
      // lane holds q_lat[t = wg*16+l16][l = mb*16+quad*4+r]
#pragma unroll
      for (int r = 0; r < 4; ++r){
        int l = mb * 16 + quad * 4 + r;
        int cs = (((l >> 3) ^ (l16 & 7)) << 3) | (l & 7);
        X0[trow * 256 + cs] = f2bf(acc[r]);
      }
    }
  }
  __syncthreads();
#pragma unroll
  for (int ks = 0; ks < 8; ++ks){
    int gl = ks * 4 + quad;
    aS[ks] = *(const short8*)&X0[trow * 256 + ((gl ^ sw_t) << 3)];
  }
  // loop-top barrier separates these reads from staging writes

  // ---- phase 1: online-softmax KV loop
  float m_t = -1e30f, l_t = 0.f;
  f32x4 oacc[16];
#pragma unroll
  for (int n = 0; n < 16; ++n) oacc[n] = (f32x4){0.f, 0.f, 0.f, 0.f};

  const u16* ckv_b  = ckv_bf + (long)b * 2048 * 256;
  const u16* ckvT_b = ckvT   + (long)b * 256 * 2048;

  for (int st = 0; st <= qt; ++st){
    __syncthreads();   // A: X0 (P/scratch) and X1 (prev ckvT) free
    // stage ckv tile -> X0 (granule-swizzled), ckvT tile -> X1 (granule-swizzled)
#pragma unroll
    for (int i = 0; i < 8; ++i){
      int idx = i * 256 + tid;               // granule id 0..2047
      int s = idx >> 5, g = idx & 31;
      int4 v = *(const int4*)&ckv_b[((long)(st * 64 + s)) * 256 + g * 8];
      *(int4*)&X0[s * 256 + (((g ^ (s & 7)) << 3))] = v;
    }
#pragma unroll
    for (int i = 0; i < 8; ++i){
      int idx = i * 256 + tid;
      int l = idx >> 3, g = idx & 7;
      int4 v = *(const int4*)&ckvT_b[(long)l * 2048 + st * 64 + g * 8];
      *(int4*)&X1[l * 64 + (((g ^ (l & 7)) << 3))] = v;
    }
    __syncthreads();   // B: tiles ready

    // S^T = ckv(A: m=s) x q_lat(B: n=t) -> sacc[mb][r]: s = st*64+mb*16+quad*4+r, t = trow
    f32x4 sacc[4];
#pragma unroll
    for (int mb = 0; mb < 4; ++mb) sacc[mb] = (f32x4){0.f, 0.f, 0.f, 0.f};
#pragma unroll
    for (int ks = 0; ks < 8; ++ks){
#pragma unroll
      for (int mb = 0; mb < 4; ++mb){
        int gl = ks * 4 + quad;
        short8 a = *(const short8*)&X0[(mb * 16 + l16) * 256 + ((gl ^ (l16 & 7)) << 3)];
        sacc[mb] = MFMA_BF16(a, aS[ks], sacc[mb], 0, 0, 0);
      }
    }
    if (st == qt){   // causal mask on diagonal tile: s > t -> -inf
      int t = qt * 64 + trow;
#pragma unroll
      for (int mb = 0; mb < 4; ++mb)
#pragma unroll
        for (int r = 0; r < 4; ++r)
          if (st * 64 + mb * 16 + quad * 4 + r > t) sacc[mb][r] = -1e30f;
    }

    // online softmax: per-lane state for t = trow (replicated across quads)
    float pm[4][4];
    {
      float rm = sacc[0][0];
#pragma unroll
      for (int mb = 0; mb < 4; ++mb)
#pragma unroll
        for (int r = 0; r < 4; ++r) rm = fmaxf(rm, sacc[mb][r]);
      rm = fmaxf(rm, __shfl_xor(rm, 16, 64));
      rm = fmaxf(rm, __shfl_xor(rm, 32, 64));
      float mnew = fmaxf(m_t, rm);
      float alpha = __expf(m_t - mnew);
      m_t = mnew;
      float rs = 0.f;
#pragma unroll
      for (int mb = 0; mb < 4; ++mb)
#pragma unroll
        for (int r = 0; r < 4; ++r){
          float pe = __expf(sacc[mb][r] - mnew);
          pm[mb][r] = pe;
          rs += pe;
        }
      rs += __shfl_xor(rs, 16, 64);
      rs += __shfl_xor(rs, 32, 64);
      l_t = l_t * alpha + rs;
      // rescale O: row r2 of oacc is t = wg*16 + quad*4 + r2 -> alpha from lane quad*4+r2
#pragma unroll
      for (int r2 = 0; r2 < 4; ++r2){
        float ar = __shfl(alpha, quad * 4 + r2, 64);
#pragma unroll
        for (int n = 0; n < 16; ++n) oacc[n][r2] *= ar;
      }
    }
    __syncthreads();   // C: S-phase reads of X0 done; P region reusable
#pragma unroll
    for (int mb = 0; mb < 4; ++mb)
#pragma unroll
      for (int r = 0; r < 4; ++r)
        X0[trow * 72 + mb * 16 + quad * 4 + r] = f2bf(pm[mb][r]);
    __syncthreads();   // D: P visible

    // O += P(A: m=t) x ckvT(B: n=l)
    {
      short8 a0 = *(const short8*)&X0[trow * 72 + quad * 8];
      short8 a1 = *(const short8*)&X0[trow * 72 + 32 + quad * 8];
#pragma unroll
      for (int n = 0; n < 16; ++n){
        int lr_ = n * 16 + l16;
        int swl = lr_ & 7;
        short8 b0 = *(const short8*)&X1[lr_ * 64 + ((quad ^ swl) << 3)];
        short8 b1 = *(const short8*)&X1[lr_ * 64 + (((4 + quad) ^ swl) << 3)];
        oacc[n] = MFMA_BF16(a0, b0, oacc[n], 0, 0, 0);
        oacc[n] = MFMA_BF16(a1, b1, oacc[n], 0, 0, 0);
      }
    }
  }

  // ---- finalize: ctx = O / l -> X0 scratch, y = ctx @ Vt
  __syncthreads();
  {
    float linv = 1.f / l_t;
#pragma unroll
    for (int r = 0; r < 4; ++r){
      float lr_ = __shfl(linv, quad * 4 + r, 64);
#pragma unroll
      for (int n = 0; n < 16; ++n) oacc[n][r] *= lr_;
    }
#pragma unroll
    for (int n = 0; n < 16; ++n)
#pragma unroll
      for (int r = 0; r < 4; ++r){
        int trw = wg * 16 + quad * 4 + r;
        int l = n * 16 + l16;
        int cs = (((l >> 3) ^ (trw & 7)) << 3) | (l & 7);
        X0[trw * 256 + cs] = f2bf(oacc[n][r]);
      }
  }
  __syncthreads();
  {
    const u16* vth = Vt + (long)h * 64 * 256;
    short8 ca[8];
#pragma unroll
    for (int ks = 0; ks < 8; ++ks){
      int gl = ks * 4 + quad;
      ca[ks] = *(const short8*)&X0[trow * 256 + ((gl ^ sw_t) << 3)];
    }
#pragma unroll
    for (int n = 0; n < 4; ++n){
      f32x4 acc = (f32x4){0.f, 0.f, 0.f, 0.f};
#pragma unroll
      for (int ks = 0; ks < 8; ++ks){
        short8 vb = *(const short8*)&vth[(n * 16 + l16) * 256 + ks * 32 + quad * 8];
        acc = MFMA_BF16(ca[ks], vb, acc, 0, 0, 0);
      }
#pragma unroll
      for (int r = 0; r < 4; ++r)
        y[(tglob + wg * 16 + quad * 4 + r) * 1024 + h * 64 + n * 16 + l16] = acc[r];
    }
  }
}

extern "C" void kernel_launch(void* const* d_in, const int* in_sizes, int n_in,
                              void* d_out, int out_size, void* d_ws, size_t ws_size,
                              hipStream_t stream)
{
  (void)in_sizes; (void)n_in; (void)out_size; (void)ws_size;
  const float* x    = (const float*)d_in[0];
  const float* Wdq  = (const float*)d_in[1];
  const float* Wuq  = (const float*)d_in[2];
  const float* Wdkv = (const float*)d_in[3];
  const float* Wuk  = (const float*)d_in[4];
  const float* Wuv  = (const float*)d_in[5];
  const float* Wo   = (const float*)d_in[6];

  float* y_out   = (float*)d_out;                      // (4,2048,1024) fp32
  float* ckv_out = y_out + (size_t)4 * 2048 * 1024;    // (4,2048,256) fp32

  char* base = (char*)d_ws;
  float* wdqT   = (float*)(base + 0);          // 1 MB, dead after keffT
  float* wuqT   = (float*)(base + 1048576);    // 1 MB, dead after pt
  float* wukT   = (float*)(base + 2097152);    // 1 MB, dead after t1T
  float* wuvT   = (float*)(base + 3145728);    // 1 MB, dead after vt
  u16*   ckvT   = (u16*)  (base + 0);          // 4 MB  (4,256,2048) after weights dead
  float* t1T    = (float*)(base + 4194304);    // 256 KB
  float* keffT  = (float*)(base + 4456448);    // 1 MB
  u16*   pt     = (u16*)  (base + 5505024);    // 2 MB  (16,256,256), 1/8 folded
  u16*   vt     = (u16*)  (base + 7602176);    // 512 KB (1024,256)
  u16*   xq     = (u16*)  (base + 8126464);    // 4 MB  (8192,256)
  u16*   ckv_bf = (u16*)  (base + 12320768);   // 4 MB  (4,2048,256) bf16

  dim3 tb(32, 8);
  k_transpose_f<<<dim3(32, 8, 1), tb, 0, stream>>>(Wdq, wdqT, 256, 1024);
  k_transpose_f<<<dim3(8, 32, 1), tb, 0, stream>>>(Wuq, wuqT, 1024, 256);
  k_transpose_f<<<dim3(8, 32, 1), tb, 0, stream>>>(Wuk, wukT, 1024, 256);
  k_transpose_f<<<dim3(8, 32, 1), tb, 0, stream>>>(Wuv, wuvT, 1024, 256);

  k_gemm_nt<<<dim3(4, 4, 1), 256, 0, stream>>>(wukT, wuqT, t1T, (u16*)0,
      256, 256, 1024, 1024, 1024, 256, 0, 0, 0, 1.f);
  k_gemm_nt<<<dim3(16, 4, 1), 256, 0, stream>>>(t1T, wdqT, keffT, (u16*)0,
      256, 1024, 256, 256, 256, 1024, 0, 0, 0, 1.f);
  k_gemm_nt<<<dim3(4, 4, 16), 256, 0, stream>>>(keffT, wuqT, (float*)0, pt,
      256, 256, 64, 1024, 1024, 256, 64, 64, 65536, 0.125f);
  k_gemm_nt<<<dim3(4, 16, 1), 256, 0, stream>>>(Wo, wuvT, (float*)0, vt,
      1024, 256, 1024, 1024, 1024, 256, 0, 0, 0, 1.f);
  k_gemm_nt<<<dim3(4, 128, 1), 256, 0, stream>>>(x, Wdq, (float*)0, xq,
      8192, 256, 1024, 1024, 1024, 256, 0, 0, 0, 1.f);
  // c_kv: fp32 to d_out AND bf16 copy for flash
  k_gemm_nt<<<dim3(4, 128, 1), 256, 0, stream>>>(x, Wdkv, ckv_out, ckv_bf,
      8192, 256, 1024, 1024, 1024, 256, 0, 0, 0, 1.f);

  k_transpose_b<<<dim3(8, 64, 4), tb, 0, stream>>>(ckv_out, ckvT,
      2048, 256, (long)2048 * 256, (long)256 * 2048);

  k_flash<<<dim3(32, 16, 4), 256, 0, stream>>>(xq, pt, ckv_bf, ckvT, vt, y_out);
}

// Round 4
// 740.005 us; speedup vs baseline: 1.7707x; 1.6102x over previous
//
#include <hip/hip_runtime.h>

typedef unsigned short u16;
typedef __attribute__((ext_vector_type(8))) short short8;
typedef __attribute__((ext_vector_type(4))) float f32x4;

#define MFMA_BF16 __builtin_amdgcn_mfma_f32_16x16x32_bf16

__device__ __forceinline__ u16 f2bf(float f){
  unsigned int u = __builtin_bit_cast(unsigned int, f);
  u += 0x7fffu + ((u >> 16) & 1u);
  return (u16)(u >> 16);
}

// async global->LDS 16B: lane i writes lds_base + i*16
__device__ __forceinline__ void gld16(const void* g, void* l){
  __builtin_amdgcn_global_load_lds(
      (const __attribute__((address_space(1))) unsigned int*)g,
      (__attribute__((address_space(3))) unsigned int*)l, 16, 0, 0);
}

// ---------------- batched fp32 transposes of the 4 weights ----------------
// z=0: Wdq (256x1024)->wdqT ; z=1..3: Wuq/Wuk/Wuv (1024x256)->T
__global__ void k_transpose4(const float* __restrict__ s0, float* __restrict__ d0,
                             const float* __restrict__ s1, float* __restrict__ d1,
                             const float* __restrict__ s2, float* __restrict__ d2,
                             const float* __restrict__ s3, float* __restrict__ d3)
{
  __shared__ float tile[32][33];
  int z = blockIdx.z;
  const float* src = z == 0 ? s0 : z == 1 ? s1 : z == 2 ? s2 : s3;
  float* dst       = z == 0 ? d0 : z == 1 ? d1 : z == 2 ? d2 : d3;
  int rows = z == 0 ? 256 : 1024, cols = z == 0 ? 1024 : 256;
  int c0 = blockIdx.x * 32, r0 = blockIdx.y * 32;
  if (c0 >= cols || r0 >= rows) return;
  int tx = threadIdx.x, ty = threadIdx.y;
#pragma unroll
  for (int i = 0; i < 4; ++i){
    int r = ty + i * 8;
    tile[r][tx] = src[(long)(r0 + r) * cols + c0 + tx];
  }
  __syncthreads();
#pragma unroll
  for (int i = 0; i < 4; ++i){
    int r = ty + i * 8;
    dst[(long)(c0 + r) * rows + r0 + tx] = tile[tx][r];
  }
}

// ---------------- NT MFMA GEMM: C[M,N] = scale * A[M,K] * B[N,K]^T ----------------
__global__ __launch_bounds__(256)
void k_gemm_nt(const float* __restrict__ A, const float* __restrict__ B,
               float* __restrict__ Cf, u16* __restrict__ Cb,
               int M, int N, int K, int lda, int ldb, int ldc,
               long sA, long sB, long sC, float scale)
{
  A += (long)blockIdx.z * sA; B += (long)blockIdx.z * sB;
  if (Cf) Cf += (long)blockIdx.z * sC;
  if (Cb) Cb += (long)blockIdx.z * sC;
  const int n0 = blockIdx.x * 64, m0 = blockIdx.y * 64;
  const int tid = threadIdx.x;
  const int wave = tid >> 6, lane = tid & 63, quad = lane >> 4, l16 = lane & 15;
  __shared__ u16 As[64 * 40];
  __shared__ u16 Bs[64 * 40];
  f32x4 acc[4];
#pragma unroll
  for (int n = 0; n < 4; ++n) acc[n] = (f32x4){0.f, 0.f, 0.f, 0.f};

  const int lr = tid >> 2;
  const int lc = (tid & 3) * 8;
  for (int k0 = 0; k0 < K; k0 += 32){
    {
      const float* pa = &A[(long)(m0 + lr) * lda + k0 + lc];
      float4 a0 = *(const float4*)pa;
      float4 a1 = *(const float4*)(pa + 4);
      short8 pk;
      pk[0]=(short)f2bf(a0.x); pk[1]=(short)f2bf(a0.y); pk[2]=(short)f2bf(a0.z); pk[3]=(short)f2bf(a0.w);
      pk[4]=(short)f2bf(a1.x); pk[5]=(short)f2bf(a1.y); pk[6]=(short)f2bf(a1.z); pk[7]=(short)f2bf(a1.w);
      *(short8*)&As[lr * 40 + lc] = pk;
      const float* pb = &B[(long)(n0 + lr) * ldb + k0 + lc];
      float4 b0 = *(const float4*)pb;
      float4 b1 = *(const float4*)(pb + 4);
      short8 qk;
      qk[0]=(short)f2bf(b0.x); qk[1]=(short)f2bf(b0.y); qk[2]=(short)f2bf(b0.z); qk[3]=(short)f2bf(b0.w);
      qk[4]=(short)f2bf(b1.x); qk[5]=(short)f2bf(b1.y); qk[6]=(short)f2bf(b1.z); qk[7]=(short)f2bf(b1.w);
      *(short8*)&Bs[lr * 40 + lc] = qk;
    }
    __syncthreads();
    short8 a = *(const short8*)&As[(wave * 16 + l16) * 40 + quad * 8];
#pragma unroll
    for (int n = 0; n < 4; ++n){
      short8 b = *(const short8*)&Bs[(n * 16 + l16) * 40 + quad * 8];
      acc[n] = MFMA_BF16(a, b, acc[n], 0, 0, 0);
    }
    __syncthreads();
  }
#pragma unroll
  for (int n = 0; n < 4; ++n)
#pragma unroll
    for (int r = 0; r < 4; ++r){
      int row = m0 + wave * 16 + quad * 4 + r;
      int col = n0 + n * 16 + l16;
      float v = acc[n][r] * scale;
      if (Cf) Cf[(long)row * ldc + col] = v;
      if (Cb) Cb[(long)row * ldc + col] = f2bf(v);
    }
}

// ---------------- fused projections: xq = x@Wdq^T (bf16), ckv = x@Wdkv^T ----------------
// (fp32 to d_out, bf16 row-major, bf16 transposed per batch)
// grid (8 ntiles, 128 mtiles): ntile<4 -> xq; else ckv.
__global__ __launch_bounds__(256)
void k_proj(const float* __restrict__ x, const float* __restrict__ Wdq,
            const float* __restrict__ Wdkv, u16* __restrict__ xq,
            float* __restrict__ ckv_f, u16* __restrict__ ckv_bf, u16* __restrict__ ckvT)
{
  const bool is_kv = blockIdx.x >= 4;
  const float* B = is_kv ? Wdkv : Wdq;
  const int n0 = (blockIdx.x & 3) * 64, m0 = blockIdx.y * 64;
  const int tid = threadIdx.x;
  const int wave = tid >> 6, lane = tid & 63, quad = lane >> 4, l16 = lane & 15;
  __shared__ u16 As[64 * 40];
  __shared__ u16 Bs[64 * 40];
  f32x4 acc[4];
#pragma unroll
  for (int n = 0; n < 4; ++n) acc[n] = (f32x4){0.f, 0.f, 0.f, 0.f};

  const int lr = tid >> 2;
  const int lc = (tid & 3) * 8;
  for (int k0 = 0; k0 < 1024; k0 += 32){
    {
      const float* pa = &x[(long)(m0 + lr) * 1024 + k0 + lc];
      float4 a0 = *(const float4*)pa;
      float4 a1 = *(const float4*)(pa + 4);
      short8 pk;
      pk[0]=(short)f2bf(a0.x); pk[1]=(short)f2bf(a0.y); pk[2]=(short)f2bf(a0.z); pk[3]=(short)f2bf(a0.w);
      pk[4]=(short)f2bf(a1.x); pk[5]=(short)f2bf(a1.y); pk[6]=(short)f2bf(a1.z); pk[7]=(short)f2bf(a1.w);
      *(short8*)&As[lr * 40 + lc] = pk;
      const float* pb = &B[(long)(n0 + lr) * 1024 + k0 + lc];
      float4 b0 = *(const float4*)pb;
      float4 b1 = *(const float4*)(pb + 4);
      short8 qk;
      qk[0]=(short)f2bf(b0.x); qk[1]=(short)f2bf(b0.y); qk[2]=(short)f2bf(b0.z); qk[3]=(short)f2bf(b0.w);
      qk[4]=(short)f2bf(b1.x); qk[5]=(short)f2bf(b1.y); qk[6]=(short)f2bf(b1.z); qk[7]=(short)f2bf(b1.w);
      *(short8*)&Bs[lr * 40 + lc] = qk;
    }
    __syncthreads();
    short8 a = *(const short8*)&As[(wave * 16 + l16) * 40 + quad * 8];
#pragma unroll
    for (int n = 0; n < 4; ++n){
      short8 b = *(const short8*)&Bs[(n * 16 + l16) * 40 + quad * 8];
      acc[n] = MFMA_BF16(a, b, acc[n], 0, 0, 0);
    }
    __syncthreads();
  }
  if (!is_kv){
#pragma unroll
    for (int n = 0; n < 4; ++n)
#pragma unroll
      for (int r = 0; r < 4; ++r){
        int row = m0 + wave * 16 + quad * 4 + r;
        int col = n0 + n * 16 + l16;
        xq[(long)row * 256 + col] = f2bf(acc[n][r]);
      }
  } else {
    const int b = (m0 >> 11);
    const int t0 = (m0 & 2047) + wave * 16 + quad * 4;
#pragma unroll
    for (int n = 0; n < 4; ++n){
      int col = n0 + n * 16 + l16;
      u16 pk[4];
#pragma unroll
      for (int r = 0; r < 4; ++r){
        int row = m0 + wave * 16 + quad * 4 + r;
        float v = acc[n][r];
        ckv_f [(long)row * 256 + col] = v;
        ckv_bf[(long)row * 256 + col] = f2bf(v);
        pk[r] = f2bf(v);
      }
      // transposed: ckvT[b][l=col][t0..t0+3] (4 consecutive u16 = one 8B store)
      *(uint2*)&ckvT[((long)b * 256 + col) * 2048 + t0] = *(uint2*)pk;
    }
  }
}

// ---------------- fused MLA flash attention (S^T formulation, async staging) ----------------
// grid (32 qtiles reversed, 16 heads, 4 batch), 256 threads (4 waves x 16 q-rows)
__global__ __launch_bounds__(256, 2)
void k_flash(const u16* __restrict__ xq, const u16* __restrict__ Pt,
             const u16* __restrict__ ckv_bf, const u16* __restrict__ ckvT,
             const u16* __restrict__ Vt, float* __restrict__ y)
{
  const int qt = 31 - blockIdx.x, h = blockIdx.y, b = blockIdx.z;
  const int tid = threadIdx.x;
  const int wg = tid >> 6, lane = tid & 63, quad = lane >> 4, l16 = lane & 15;

  __shared__ u16 X0[64 * 256];   // ckv tile (swizzled) / q_lat scratch / P / ctx scratch
  __shared__ u16 X1[256 * 64];   // ckvT tile (swizzled)

  const int trow = wg * 16 + l16;
  const long tglob = (long)b * 2048 + qt * 64;
  const int sw_t = trow & 7;

  const u16* ckv_b  = ckv_bf + (long)b * 2048 * 256;
  const u16* ckvT_b = ckvT   + (long)b * 256 * 2048;

  // per-lane async-staging source pointers (this wave stages chunks wg*8+j)
  const u16* srcA[8]; const u16* srcB[8];
  {
    int l5 = lane >> 5, g32 = lane & 31;
#pragma unroll
    for (int j = 0; j < 8; ++j){
      int s = (wg * 8 + j) * 2 + l5;               // 0..63
      int g = g32 ^ (s & 7);                       // source granule (swizzle on read side)
      srcA[j] = ckv_b + (long)s * 256 + g * 8;     // advance st*16384 (u16) per iter
    }
    int l3 = lane >> 3, g8 = lane & 7;
#pragma unroll
    for (int j = 0; j < 8; ++j){
      int l = (wg * 8 + j) * 8 + l3;               // 0..255
      int g = g8 ^ (l & 7);
      srcB[j] = ckvT_b + (long)l * 2048 + g * 8;   // advance st*64 (u16) per iter
    }
  }

  // ---- phase 0: q_lat^T = Pt[h](A) x xq(B); park q_lat in X0, read back B-frags aS
  short8 aS[8];
  {
    short8 bq[8];
    const u16* xr = xq + (tglob + trow) * 256;
#pragma unroll
    for (int ks = 0; ks < 8; ++ks)
      bq[ks] = *(const short8*)&xr[ks * 32 + quad * 8];
    const u16* pth = Pt + (long)h * 65536;
#pragma unroll
    for (int mb = 0; mb < 16; ++mb){
      f32x4 acc = (f32x4){0.f, 0.f, 0.f, 0.f};
#pragma unroll
      for (int ks = 0; ks < 8; ++ks){
        short8 pa = *(const short8*)&pth[(mb * 16 + l16) * 256 + ks * 32 + quad * 8];
        acc = MFMA_BF16(pa, bq[ks], acc, 0, 0, 0);
      }
#pragma unroll
      for (int r = 0; r < 4; ++r){
        int l = mb * 16 + quad * 4 + r;
        int cs = (((l >> 3) ^ (l16 & 7)) << 3) | (l & 7);
        X0[trow * 256 + cs] = f2bf(acc[r]);
      }
    }
  }
  __syncthreads();
#pragma unroll
  for (int ks = 0; ks < 8; ++ks){
    int gl = ks * 4 + quad;
    aS[ks] = *(const short8*)&X0[trow * 256 + ((gl ^ sw_t) << 3)];
  }

  // ---- phase 1: online-softmax KV loop
  float m_t = -1e30f, l_t = 0.f;
  f32x4 oacc[16];
#pragma unroll
  for (int n = 0; n < 16; ++n) oacc[n] = (f32x4){0.f, 0.f, 0.f, 0.f};

  for (int st = 0; st <= qt; ++st){
    __syncthreads();   // A: X0 (P/scratch) and X1 (prev ckvT) free
    // async-stage ckv tile -> X0, ckvT tile -> X1 (swizzle folded into source addr)
#pragma unroll
    for (int j = 0; j < 8; ++j)
      gld16(srcA[j] + (long)st * 16384, &X0[(wg * 8 + j) * 512]);
#pragma unroll
    for (int j = 0; j < 8; ++j)
      gld16(srcB[j] + st * 64, &X1[(wg * 8 + j) * 512]);
    __syncthreads();   // B: vmcnt(0) drained by compiler; tiles ready

    // S^T = ckv(A: m=s) x q_lat(B: n=t)
    f32x4 sacc[4];
#pragma unroll
    for (int mb = 0; mb < 4; ++mb) sacc[mb] = (f32x4){0.f, 0.f, 0.f, 0.f};
#pragma unroll
    for (int ks = 0; ks < 8; ++ks){
#pragma unroll
      for (int mb = 0; mb < 4; ++mb){
        int gl = ks * 4 + quad;
        short8 a = *(const short8*)&X0[(mb * 16 + l16) * 256 + ((gl ^ (l16 & 7)) << 3)];
        sacc[mb] = MFMA_BF16(a, aS[ks], sacc[mb], 0, 0, 0);
      }
    }
    if (st == qt){   // causal mask on diagonal tile: s > t -> -inf
      int t = qt * 64 + trow;
#pragma unroll
      for (int mb = 0; mb < 4; ++mb)
#pragma unroll
        for (int r = 0; r < 4; ++r)
          if (st * 64 + mb * 16 + quad * 4 + r > t) sacc[mb][r] = -1e30f;
    }

    // online softmax: per-lane state for t = trow (replicated across quads)
    float pm[4][4];
    {
      float rm = sacc[0][0];
#pragma unroll
      for (int mb = 0; mb < 4; ++mb)
#pragma unroll
        for (int r = 0; r < 4; ++r) rm = fmaxf(rm, sacc[mb][r]);
      rm = fmaxf(rm, __shfl_xor(rm, 16, 64));
      rm = fmaxf(rm, __shfl_xor(rm, 32, 64));
      float mnew = fmaxf(m_t, rm);
      float alpha = __expf(m_t - mnew);
      m_t = mnew;
      float rs = 0.f;
#pragma unroll
      for (int mb = 0; mb < 4; ++mb)
#pragma unroll
        for (int r = 0; r < 4; ++r){
          float pe = __expf(sacc[mb][r] - mnew);
          pm[mb][r] = pe;
          rs += pe;
        }
      rs += __shfl_xor(rs, 16, 64);
      rs += __shfl_xor(rs, 32, 64);
      l_t = l_t * alpha + rs;
#pragma unroll
      for (int r2 = 0; r2 < 4; ++r2){
        float ar = __shfl(alpha, quad * 4 + r2, 64);
#pragma unroll
        for (int n = 0; n < 16; ++n) oacc[n][r2] *= ar;
      }
    }
    __syncthreads();   // C: S-phase reads of X0 done; P region reusable
#pragma unroll
    for (int mb = 0; mb < 4; ++mb)
#pragma unroll
      for (int r = 0; r < 4; ++r)
        X0[trow * 72 + mb * 16 + quad * 4 + r] = f2bf(pm[mb][r]);
    __syncthreads();   // D: P visible

    // O += P(A: m=t) x ckvT(B: n=l)
    {
      short8 a0 = *(const short8*)&X0[trow * 72 + quad * 8];
      short8 a1 = *(const short8*)&X0[trow * 72 + 32 + quad * 8];
#pragma unroll
      for (int n = 0; n < 16; ++n){
        int lr_ = n * 16 + l16;
        int swl = lr_ & 7;
        short8 b0 = *(const short8*)&X1[lr_ * 64 + ((quad ^ swl) << 3)];
        short8 b1 = *(const short8*)&X1[lr_ * 64 + (((4 + quad) ^ swl) << 3)];
        oacc[n] = MFMA_BF16(a0, b0, oacc[n], 0, 0, 0);
        oacc[n] = MFMA_BF16(a1, b1, oacc[n], 0, 0, 0);
      }
    }
  }

  // ---- finalize: ctx = O / l -> X0 scratch, y = ctx @ Vt
  __syncthreads();
  {
    float linv = 1.f / l_t;
#pragma unroll
    for (int r = 0; r < 4; ++r){
      float lr_ = __shfl(linv, quad * 4 + r, 64);
#pragma unroll
      for (int n = 0; n < 16; ++n) oacc[n][r] *= lr_;
    }
#pragma unroll
    for (int n = 0; n < 16; ++n)
#pragma unroll
      for (int r = 0; r < 4; ++r){
        int trw = wg * 16 + quad * 4 + r;
        int l = n * 16 + l16;
        int cs = (((l >> 3) ^ (trw & 7)) << 3) | (l & 7);
        X0[trw * 256 + cs] = f2bf(oacc[n][r]);
      }
  }
  __syncthreads();
  {
    const u16* vth = Vt + (long)h * 64 * 256;
    short8 ca[8];
#pragma unroll
    for (int ks = 0; ks < 8; ++ks){
      int gl = ks * 4 + quad;
      ca[ks] = *(const short8*)&X0[trow * 256 + ((gl ^ sw_t) << 3)];
    }
#pragma unroll
    for (int n = 0; n < 4; ++n){
      f32x4 acc = (f32x4){0.f, 0.f, 0.f, 0.f};
#pragma unroll
      for (int ks = 0; ks < 8; ++ks){
        short8 vb = *(const short8*)&vth[(n * 16 + l16) * 256 + ks * 32 + quad * 8];
        acc = MFMA_BF16(ca[ks], vb, acc, 0, 0, 0);
      }
#pragma unroll
      for (int r = 0; r < 4; ++r)
        y[(tglob + wg * 16 + quad * 4 + r) * 1024 + h * 64 + n * 16 + l16] = acc[r];
    }
  }
}

extern "C" void kernel_launch(void* const* d_in, const int* in_sizes, int n_in,
                              void* d_out, int out_size, void* d_ws, size_t ws_size,
                              hipStream_t stream)
{
  (void)in_sizes; (void)n_in; (void)out_size; (void)ws_size;
  const float* x    = (const float*)d_in[0];
  const float* Wdq  = (const float*)d_in[1];
  const float* Wuq  = (const float*)d_in[2];
  const float* Wdkv = (const float*)d_in[3];
  const float* Wuk  = (const float*)d_in[4];
  const float* Wuv  = (const float*)d_in[5];
  const float* Wo   = (const float*)d_in[6];

  float* y_out   = (float*)d_out;                      // (4,2048,1024) fp32
  float* ckv_out = y_out + (size_t)4 * 2048 * 1024;    // (4,2048,256) fp32

  char* base = (char*)d_ws;
  float* wdqT   = (float*)(base + 0);          // 1 MB, dead after keffT
  float* wuqT   = (float*)(base + 1048576);    // 1 MB, dead after pt
  float* wukT   = (float*)(base + 2097152);    // 1 MB, dead after t1T
  float* wuvT   = (float*)(base + 3145728);    // 1 MB, dead after vt
  u16*   ckvT   = (u16*)  (base + 0);          // 4 MB (4,256,2048) written after weights dead
  float* t1T    = (float*)(base + 4194304);    // 256 KB
  float* keffT  = (float*)(base + 4456448);    // 1 MB
  u16*   pt     = (u16*)  (base + 5505024);    // 2 MB (16,256,256), 1/8 folded
  u16*   vt     = (u16*)  (base + 7602176);    // 512 KB (1024,256)
  u16*   xq     = (u16*)  (base + 8126464);    // 4 MB (8192,256)
  u16*   ckv_bf = (u16*)  (base + 12320768);   // 4 MB (4,2048,256) bf16

  k_transpose4<<<dim3(32, 32, 4), dim3(32, 8), 0, stream>>>(
      Wdq, wdqT, Wuq, wuqT, Wuk, wukT, Wuv, wuvT);

  k_gemm_nt<<<dim3(4, 4, 1), 256, 0, stream>>>(wukT, wuqT, t1T, (u16*)0,
      256, 256, 1024, 1024, 1024, 256, 0, 0, 0, 1.f);
  k_gemm_nt<<<dim3(16, 4, 1), 256, 0, stream>>>(t1T, wdqT, keffT, (u16*)0,
      256, 1024, 256, 256, 256, 1024, 0, 0, 0, 1.f);
  k_gemm_nt<<<dim3(4, 4, 16), 256, 0, stream>>>(keffT, wuqT, (float*)0, pt,
      256, 256, 64, 1024, 1024, 256, 64, 64, 65536, 0.125f);
  k_gemm_nt<<<dim3(4, 16, 1), 256, 0, stream>>>(Wo, wuvT, (float*)0, vt,
      1024, 256, 1024, 1024, 1024, 256, 0, 0, 0, 1.f);

  // fused: xq (bf16), ckv (fp32 -> d_out, bf16, bf16-transposed) — after ckvT region is free
  k_proj<<<dim3(8, 128), 256, 0, stream>>>(x, Wdq, Wdkv, xq, ckv_out, ckv_bf, ckvT);

  k_flash<<<dim3(32, 16, 4), 256, 0, stream>>>(xq, pt, ckv_bf, ckvT, vt, y_out);
}